// Round 8
// baseline (281.212 us; speedup 1.0000x reference)
//
#include <hip/hip_runtime.h>
#include <hip/hip_bf16.h>
#include <stdint.h>

typedef short short8 __attribute__((ext_vector_type(8)));
typedef float f32x4 __attribute__((ext_vector_type(4)));
typedef float f32x2 __attribute__((ext_vector_type(2)));

__device__ __forceinline__ unsigned short f2bf(float f) {
    unsigned u = __float_as_uint(f);
    u += 0x7fff + ((u >> 16) & 1);           // RNE
    return (unsigned short)(u >> 16);
}
__device__ __forceinline__ float bf2f(unsigned short h) {
    return __uint_as_float(((unsigned)h) << 16);
}

__device__ __forceinline__ void gload_lds16(const void* g, void* l) {
    __builtin_amdgcn_global_load_lds(
        (const __attribute__((address_space(1))) void*)g,
        (__attribute__((address_space(3))) void*)l, 16, 0, 0);
}

// ---------------- cast x (fp32 -> bf16 bits) ----------------
__global__ void cast_x_kernel(const float* __restrict__ x, unsigned short* __restrict__ xb, int n) {
    int i = (blockIdx.x * blockDim.x + threadIdx.x) * 4;
    int stride = gridDim.x * blockDim.x * 4;
    for (; i < n; i += stride) {
        float4 f = *(const float4*)(x + i);
        ushort4 o;
        o.x = f2bf(f.x); o.y = f2bf(f.y); o.z = f2bf(f.z); o.w = f2bf(f.w);
        *(ushort4*)(xb + i) = o;
    }
}

// ---------------- transpose + cast weights: W[k][n] fp32 -> Wt[n][k] bf16 ----------------
__global__ void transpose_cast_kernel(const float* __restrict__ W, unsigned short* __restrict__ Wt,
                                      int K, int N) {
    __shared__ unsigned short tile[32][33];
    int k0 = blockIdx.x * 32, n0 = blockIdx.y * 32;
    int tx = threadIdx.x & 31, ty = threadIdx.x >> 5;   // 32 x 8
#pragma unroll
    for (int i = 0; i < 32; i += 8)
        tile[ty + i][tx] = f2bf(W[(size_t)(k0 + ty + i) * N + n0 + tx]);
    __syncthreads();
#pragma unroll
    for (int i = 0; i < 32; i += 8)
        Wt[(size_t)(n0 + ty + i) * K + k0 + tx] = tile[tx][ty + i];
}

// ---------------- persistent fused QKV GEMM: 256 blocks (1/CU), 3 assignments/block ----
// Each block owns one m-tile (256 rows of A) and 3 consecutive n-panels (p0..p0+2 of
// wqkvt; groups of 3 never cross an m-tile's 12 panels).  The K-pipeline runs as ONE
// continuous 48-step stream (gs = seg*16 + t): buffer parity, per-step counted
// vmcnt(6), and the read-then-stage phase pattern are invariant across segment
// boundaries, so the pipeline fills once and drains once (round-6 lesson: 3 separate
// generations paid 3 fills/drains + ragged tails; LDS=128KB forces 1 block/CU, so
// intra-dispatch continuity is the only occupancy lever).  gA constant per block ->
// 3x L2 reuse of A.  Per-segment epilogue overlaps next segment's prefetch.
// Arithmetic per output identical to the split version -> bit-identical results.
__global__ __launch_bounds__(512, 4)
void gemmQKV(const unsigned short* __restrict__ A, const unsigned short* __restrict__ B,
             unsigned short* __restrict__ qb, unsigned short* __restrict__ kb,
             unsigned short* __restrict__ vtb, float* __restrict__ sq, float* __restrict__ sk) {
    __shared__ unsigned short Ssh[65536];   // A bufs: [0,32768) u16; B bufs: [32768,65536)
    const int tid = threadIdx.x;
    const int w = tid >> 6, lane = tid & 63;
    const int lr = lane & 15, lg = lane >> 4, r7 = lane & 7;
    const int wr = w >> 2, wc = w & 3;                  // 2x4 wave grid, wave tile 128x64
    const int orig = blockIdx.x;                        // 256 blocks
    const int lgc = (orig & 7) * 32 + (orig >> 3);      // XCD-chunked (256 % 8 == 0)
    const int m0 = (lgc >> 2) * 256;                    // m-tile (lgc/4)
    const int p0 = (lgc & 3) * 3;                       // first of 3 consecutive panels
    const int srow8 = lane >> 3;
    const int sgrp = (lane & 7) ^ srow8;                // pre-swizzled 16B group
    const unsigned short* gA = A + (size_t)(m0 + w * 16 + srow8) * 1024 + sgrp * 8;
    const unsigned short* gB = B + (size_t)(p0 * 256 + w * 16 + srow8) * 1024 + sgrp * 8;

    f32x4 acc[8][4] = {};

    // stage one half-tile (2 gloads) for global step ST: HALF 0/1 = A rows 0-127 /
    // 128-255; HALF 2/3 = B likewise.  tile = ST>>4 selects the B panel (A constant).
#define SH(HALF, ST) {                                                                   \
        const int t_ = (ST) >> 4, k_ = ((ST) & 15) * 64;                                 \
        const unsigned short* gp_ = ((HALF) < 2 ? gA : gB + (size_t)t_ * 262144) +       \
                                    (size_t)(((HALF) & 1) * 128) * 1024 + k_;            \
        unsigned short* lp_ = Ssh + ((HALF) < 2 ? 0 : 32768) + ((ST) & 1) * 16384 +      \
                              ((HALF) & 1) * 8192 + w * 1024;                            \
        gload_lds16(gp_, lp_);                                                           \
        gload_lds16(gp_ + 8192, lp_ + 512);                                              \
    }

    // prologue: step0 complete + step1 halves 0-2 (h3 of step1 staged in gs=0 P1)
    SH(0, 0) SH(1, 0) SH(2, 0) SH(3, 0)
    SH(0, 1) SH(1, 1) SH(2, 1)
    asm volatile("s_waitcnt vmcnt(6)" ::: "memory");    // 8 oldest done = step0 resident
    __builtin_amdgcn_sched_barrier(0);
    __builtin_amdgcn_s_barrier();

    for (int seg = 0; seg < 3; ++seg) {
        const int p = p0 + seg;
        const int mode = p >> 2;                        // 0:q 1:k 2:vT
        const int n0 = (p & 3) * 256;                   // local col in [0,1024)

#pragma unroll 2
        for (int t = 0; t < 16; ++t) {
            const int gs = (seg << 4) | t;              // global step 0..47
            const int cur = gs & 1;
            const unsigned short* Ab = Ssh + cur * 16384;
            const unsigned short* Bb = Ssh + 32768 + cur * 16384;
            short8 af[8][2], bf[4][2];

            // ---- P1: read af0-3 + bf0-1 (12) ; stage h3(gs+1) ----
#pragma unroll
            for (int mi = 0; mi < 4; ++mi)
#pragma unroll
                for (int kk = 0; kk < 2; ++kk)
                    af[mi][kk] = *(const short8*)(Ab + (wr * 128 + mi * 16 + lr) * 64 +
                                                  (((kk << 2) | lg) ^ r7) * 8);
#pragma unroll
            for (int ni = 0; ni < 2; ++ni)
#pragma unroll
                for (int kk = 0; kk < 2; ++kk)
                    bf[ni][kk] = *(const short8*)(Bb + (wc * 64 + ni * 16 + lr) * 64 +
                                                  (((kk << 2) | lg) ^ r7) * 8);
            if (gs + 1 < 48) { SH(3, gs + 1) }
            asm volatile("s_waitcnt lgkmcnt(8)" ::: "memory");
            __builtin_amdgcn_sched_barrier(0);
            __builtin_amdgcn_s_barrier();
            asm volatile("s_waitcnt lgkmcnt(0)" ::: "memory");
            __builtin_amdgcn_sched_barrier(0);
            __builtin_amdgcn_s_setprio(1);
#pragma unroll
            for (int mi = 0; mi < 4; ++mi)
#pragma unroll
                for (int ni = 0; ni < 2; ++ni)
#pragma unroll
                    for (int kk = 0; kk < 2; ++kk)
                        acc[mi][ni] = __builtin_amdgcn_mfma_f32_16x16x32_bf16(
                            af[mi][kk], bf[ni][kk], acc[mi][ni], 0, 0, 0);
            __builtin_amdgcn_s_setprio(0);
            __builtin_amdgcn_s_barrier();

            // ---- P2: read af4-7 (8) ; stage h0(gs+2) ----
#pragma unroll
            for (int mi = 4; mi < 8; ++mi)
#pragma unroll
                for (int kk = 0; kk < 2; ++kk)
                    af[mi][kk] = *(const short8*)(Ab + (wr * 128 + mi * 16 + lr) * 64 +
                                                  (((kk << 2) | lg) ^ r7) * 8);
            if (gs + 2 < 48) { SH(0, gs + 2) }
            __builtin_amdgcn_s_barrier();
            asm volatile("s_waitcnt lgkmcnt(0)" ::: "memory");
            __builtin_amdgcn_sched_barrier(0);
            __builtin_amdgcn_s_setprio(1);
#pragma unroll
            for (int mi = 4; mi < 8; ++mi)
#pragma unroll
                for (int ni = 0; ni < 2; ++ni)
#pragma unroll
                    for (int kk = 0; kk < 2; ++kk)
                        acc[mi][ni] = __builtin_amdgcn_mfma_f32_16x16x32_bf16(
                            af[mi][kk], bf[ni][kk], acc[mi][ni], 0, 0, 0);
            __builtin_amdgcn_s_setprio(0);
            __builtin_amdgcn_s_barrier();

            // ---- P3: read bf2-3 (4) ; stage h1(gs+2) ----
#pragma unroll
            for (int ni = 2; ni < 4; ++ni)
#pragma unroll
                for (int kk = 0; kk < 2; ++kk)
                    bf[ni][kk] = *(const short8*)(Bb + (wc * 64 + ni * 16 + lr) * 64 +
                                                  (((kk << 2) | lg) ^ r7) * 8);
            if (gs + 2 < 48) { SH(1, gs + 2) }
            __builtin_amdgcn_s_barrier();
            asm volatile("s_waitcnt lgkmcnt(0)" ::: "memory");
            __builtin_amdgcn_sched_barrier(0);
            __builtin_amdgcn_s_setprio(1);
#pragma unroll
            for (int mi = 4; mi < 8; ++mi)
#pragma unroll
                for (int ni = 2; ni < 4; ++ni)
#pragma unroll
                    for (int kk = 0; kk < 2; ++kk)
                        acc[mi][ni] = __builtin_amdgcn_mfma_f32_16x16x32_bf16(
                            af[mi][kk], bf[ni][kk], acc[mi][ni], 0, 0, 0);
            __builtin_amdgcn_s_setprio(0);
            __builtin_amdgcn_s_barrier();

            // ---- P4: stage h2(gs+2) ; MFMA from held regs ----
            if (gs + 2 < 48) { SH(2, gs + 2) }
            __builtin_amdgcn_s_setprio(1);
#pragma unroll
            for (int mi = 0; mi < 4; ++mi)
#pragma unroll
                for (int ni = 2; ni < 4; ++ni)
#pragma unroll
                    for (int kk = 0; kk < 2; ++kk)
                        acc[mi][ni] = __builtin_amdgcn_mfma_f32_16x16x32_bf16(
                            af[mi][kk], bf[ni][kk], acc[mi][ni], 0, 0, 0);
            __builtin_amdgcn_s_setprio(0);
            if (gs < 46) {
                asm volatile("s_waitcnt vmcnt(6)" ::: "memory");   // step gs+1 resident
                __builtin_amdgcn_sched_barrier(0);
                __builtin_amdgcn_s_barrier();
            } else if (gs == 46) {
                asm volatile("s_waitcnt vmcnt(0)" ::: "memory");   // step 47 fully resident
                __builtin_amdgcn_sched_barrier(0);
                __builtin_amdgcn_s_barrier();
            }
        }

        // ---- per-segment epilogue (runtime mode); overlaps next segment's prefetch ----
        if (mode == 2) {
#pragma unroll
            for (int mi = 0; mi < 8; ++mi)
#pragma unroll
                for (int ni = 0; ni < 4; ++ni) {
                    // vT [bh][u][d][tloc]: pack (r, r+1) -> u32 (tl, tl+1 adjacent)
                    int gm0 = m0 + wr * 128 + mi * 16 + lg * 4;
                    int gn = n0 + wc * 64 + ni * 16 + lr;
                    int b = gm0 >> 12, tt0 = gm0 & 4095, h = gn >> 7, dl = gn & 127;
                    int u = tt0 >> 7, tl0 = tt0 & 127;
                    size_t base = (size_t)(b * 8 + h) * 524288 + (size_t)u * 16384 +
                                  dl * 128 + tl0;
#pragma unroll
                    for (int r = 0; r < 4; r += 2) {
                        unsigned pk = (unsigned)f2bf(acc[mi][ni][r]) |
                                      ((unsigned)f2bf(acc[mi][ni][r + 1]) << 16);
                        *(unsigned*)(vtb + base + r) = pk;
                    }
                }
        } else {
            unsigned short* obf = (mode == 0) ? qb : kb;
            const float osc = (mode == 0) ? 0.08838834764831845f : 1.0f;
#pragma unroll
            for (int mi = 0; mi < 8; ++mi)
#pragma unroll
                for (int ni = 0; ni < 4; ++ni)
#pragma unroll
                    for (int r = 0; r < 4; ++r) {
                        int gm = m0 + wr * 128 + mi * 16 + lg * 4 + r;
                        int gn = n0 + wc * 64 + ni * 16 + lr;
                        int b = gm >> 12, tt = gm & 4095, h = gn >> 7, dl = gn & 127;
                        obf[(size_t)(b * 8 + h) * 524288 + (size_t)tt * 128 + dl] =
                            f2bf(acc[mi][ni][r] * osc);
                    }
            // fused bucket means: each (bh,u,d) owned by exactly one block & wave
            float* of = (mode == 0) ? sq : sk;
            const float sc = ((mode == 0) ? 0.08838834764831845f : 1.0f) / 128.f;
#pragma unroll
            for (int ni = 0; ni < 4; ++ni) {
                float ssum = 0.f;
#pragma unroll
                for (int mi = 0; mi < 8; ++mi)
#pragma unroll
                    for (int r = 0; r < 4; ++r) ssum += acc[mi][ni][r];
                ssum += __shfl_xor(ssum, 16);
                ssum += __shfl_xor(ssum, 32);
                if (lane < 16) {
                    int gn = n0 + wc * 64 + ni * 16 + lr;
                    int h = gn >> 7, dl = gn & 127;
                    int bh = (m0 >> 12) * 8 + h;
                    int u = ((m0 & 4095) >> 7) + wr;
                    of[(size_t)(bh * 32 + u) * 128 + dl] = ssum * sc;
                }
            }
        }

        // reset accumulators for next segment
#pragma unroll
        for (int mi = 0; mi < 8; ++mi)
#pragma unroll
            for (int ni = 0; ni < 4; ++ni)
                acc[mi][ni] = f32x4{0.f, 0.f, 0.f, 0.f};
    }
#undef SH
}

// ---------------- output GEMM (MODE 3 only): fp32 d_out [m][n] + bias[n] --------------
__global__ __launch_bounds__(512, 2)
void gemmOut(const unsigned short* __restrict__ A, const unsigned short* __restrict__ B,
             float* __restrict__ of, const float* __restrict__ bias) {
    __shared__ unsigned short Ssh[65536];
    const int tid = threadIdx.x;
    const int w = tid >> 6, lane = tid & 63;
    const int lr = lane & 15, lg = lane >> 4, r7 = lane & 7;
    const int wr = w >> 2, wc = w & 3;
    const int orig = blockIdx.x;                        // 256 blocks
    const int lgc = (orig & 7) * 32 + (orig >> 3);
    const int m0 = (lgc >> 2) * 256, n0 = (lgc & 3) * 256;
    const int srow8 = lane >> 3;
    const int sgrp = (lane & 7) ^ srow8;
    const unsigned short* gA = A + (size_t)(m0 + w * 16 + srow8) * 1024 + sgrp * 8;
    const unsigned short* gB = B + (size_t)(n0 + w * 16 + srow8) * 1024 + sgrp * 8;

    f32x4 acc[8][4] = {};

#define SH(BUF, HALF, KT) {                                                              \
        const unsigned short* gp_ = ((HALF) < 2 ? gA : gB) +                             \
                                    (size_t)(((HALF) & 1) * 128) * 1024 + (KT);          \
        unsigned short* lp_ = Ssh + ((HALF) < 2 ? 0 : 32768) + (BUF) * 16384 +           \
                              ((HALF) & 1) * 8192 + w * 1024;                            \
        gload_lds16(gp_, lp_);                                                           \
        gload_lds16(gp_ + 8192, lp_ + 512);                                              \
    }

    SH(0, 0, 0) SH(0, 1, 0) SH(0, 2, 0) SH(0, 3, 0)
    SH(1, 0, 64) SH(1, 1, 64) SH(1, 2, 64)
    asm volatile("s_waitcnt vmcnt(6)" ::: "memory");
    __builtin_amdgcn_sched_barrier(0);
    __builtin_amdgcn_s_barrier();

#pragma unroll 2
    for (int t = 0; t < 16; ++t) {
        const int cur = t & 1;
        const unsigned short* Ab = Ssh + cur * 16384;
        const unsigned short* Bb = Ssh + 32768 + cur * 16384;
        const int kt1 = (t + 1) * 64, kt2 = (t + 2) * 64;
        short8 af[8][2], bf[4][2];

#pragma unroll
        for (int mi = 0; mi < 4; ++mi)
#pragma unroll
            for (int kk = 0; kk < 2; ++kk)
                af[mi][kk] = *(const short8*)(Ab + (wr * 128 + mi * 16 + lr) * 64 +
                                              (((kk << 2) | lg) ^ r7) * 8);
#pragma unroll
        for (int ni = 0; ni < 2; ++ni)
#pragma unroll
            for (int kk = 0; kk < 2; ++kk)
                bf[ni][kk] = *(const short8*)(Bb + (wc * 64 + ni * 16 + lr) * 64 +
                                              (((kk << 2) | lg) ^ r7) * 8);
        if (t + 1 < 16) { SH(cur ^ 1, 3, kt1) }
        asm volatile("s_waitcnt lgkmcnt(8)" ::: "memory");
        __builtin_amdgcn_sched_barrier(0);
        __builtin_amdgcn_s_barrier();
        asm volatile("s_waitcnt lgkmcnt(0)" ::: "memory");
        __builtin_amdgcn_sched_barrier(0);
        __builtin_amdgcn_s_setprio(1);
#pragma unroll
        for (int mi = 0; mi < 4; ++mi)
#pragma unroll
            for (int ni = 0; ni < 2; ++ni)
#pragma unroll
                for (int kk = 0; kk < 2; ++kk)
                    acc[mi][ni] = __builtin_amdgcn_mfma_f32_16x16x32_bf16(af[mi][kk], bf[ni][kk],
                                                                          acc[mi][ni], 0, 0, 0);
        __builtin_amdgcn_s_setprio(0);
        __builtin_amdgcn_s_barrier();

#pragma unroll
        for (int mi = 4; mi < 8; ++mi)
#pragma unroll
            for (int kk = 0; kk < 2; ++kk)
                af[mi][kk] = *(const short8*)(Ab + (wr * 128 + mi * 16 + lr) * 64 +
                                              (((kk << 2) | lg) ^ r7) * 8);
        if (t + 2 < 16) { SH(cur, 0, kt2) }
        __builtin_amdgcn_s_barrier();
        asm volatile("s_waitcnt lgkmcnt(0)" ::: "memory");
        __builtin_amdgcn_sched_barrier(0);
        __builtin_amdgcn_s_setprio(1);
#pragma unroll
        for (int mi = 4; mi < 8; ++mi)
#pragma unroll
            for (int ni = 0; ni < 2; ++ni)
#pragma unroll
                for (int kk = 0; kk < 2; ++kk)
                    acc[mi][ni] = __builtin_amdgcn_mfma_f32_16x16x32_bf16(af[mi][kk], bf[ni][kk],
                                                                          acc[mi][ni], 0, 0, 0);
        __builtin_amdgcn_s_setprio(0);
        __builtin_amdgcn_s_barrier();

#pragma unroll
        for (int ni = 2; ni < 4; ++ni)
#pragma unroll
            for (int kk = 0; kk < 2; ++kk)
                bf[ni][kk] = *(const short8*)(Bb + (wc * 64 + ni * 16 + lr) * 64 +
                                              (((kk << 2) | lg) ^ r7) * 8);
        if (t + 2 < 16) { SH(cur, 1, kt2) }
        __builtin_amdgcn_s_barrier();
        asm volatile("s_waitcnt lgkmcnt(0)" ::: "memory");
        __builtin_amdgcn_sched_barrier(0);
        __builtin_amdgcn_s_setprio(1);
#pragma unroll
        for (int mi = 4; mi < 8; ++mi)
#pragma unroll
            for (int ni = 2; ni < 4; ++ni)
#pragma unroll
                for (int kk = 0; kk < 2; ++kk)
                    acc[mi][ni] = __builtin_amdgcn_mfma_f32_16x16x32_bf16(af[mi][kk], bf[ni][kk],
                                                                          acc[mi][ni], 0, 0, 0);
        __builtin_amdgcn_s_setprio(0);
        __builtin_amdgcn_s_barrier();

        if (t + 2 < 16) { SH(cur, 2, kt2) }
        __builtin_amdgcn_s_setprio(1);
#pragma unroll
        for (int mi = 0; mi < 4; ++mi)
#pragma unroll
            for (int ni = 2; ni < 4; ++ni)
#pragma unroll
                for (int kk = 0; kk < 2; ++kk)
                    acc[mi][ni] = __builtin_amdgcn_mfma_f32_16x16x32_bf16(af[mi][kk], bf[ni][kk],
                                                                          acc[mi][ni], 0, 0, 0);
        __builtin_amdgcn_s_setprio(0);
        if (t < 14) {
            asm volatile("s_waitcnt vmcnt(6)" ::: "memory");
            __builtin_amdgcn_sched_barrier(0);
            __builtin_amdgcn_s_barrier();
        } else if (t == 14) {
            asm volatile("s_waitcnt vmcnt(0)" ::: "memory");
            __builtin_amdgcn_sched_barrier(0);
            __builtin_amdgcn_s_barrier();
        }
    }
#undef SH

#pragma unroll
    for (int mi = 0; mi < 8; ++mi)
#pragma unroll
        for (int ni = 0; ni < 4; ++ni)
#pragma unroll
            for (int r = 0; r < 4; ++r) {
                int gm = m0 + wr * 128 + mi * 16 + lg * 4 + r;
                int gn = n0 + wc * 64 + ni * 16 + lr;
                of[(size_t)gm * 1024 + gn] = acc[mi][ni][r] + bias[gn];
            }
}

// ---------------- sortnet: R = softmax(sq.sk^T) (scale baked into q/sq) ----------------
__global__ void sortnet_kernel(const float* __restrict__ sq, const float* __restrict__ sk,
                               float* __restrict__ R) {
    __shared__ float qs[32 * 129];
    __shared__ float ks[32 * 129];
    int bh = blockIdx.x, tid = threadIdx.x;
    for (int i = tid; i < 4096; i += 1024) {
        int row = i >> 7, col = i & 127;
        qs[row * 129 + col] = sq[(size_t)bh * 4096 + i];
        ks[row * 129 + col] = sk[(size_t)bh * 4096 + i];
    }
    __syncthreads();
    int u = tid >> 5, v = tid & 31;
    float dot = 0.f;
    for (int d = 0; d < 128; ++d) dot += qs[u * 129 + d] * ks[v * 129 + d];
    float mx = dot;
    for (int m = 16; m >= 1; m >>= 1) mx = fmaxf(mx, __shfl_xor(mx, m, 32));
    float e = __expf(dot - mx);
    float s = e;
    for (int m = 16; m >= 1; m >>= 1) s += __shfl_xor(s, m, 32);
    R[(size_t)bh * 1024 + u * 32 + v] = e / s;
}

// ---------------- mix: bkr[u] = sum_v R[u][v] k[v]; bvrT likewise ----------------
__global__ __launch_bounds__(256, 4)
void mix_kernel(const unsigned short* __restrict__ k, const unsigned short* __restrict__ vT,
                const float* __restrict__ R, unsigned short* __restrict__ bkr,
                unsigned short* __restrict__ bvrT) {
    const int bid = blockIdx.x;                  // 2048 blocks
    const int arr = bid & 1;                     // 0: K, 1: V (interleaved)
    const int rest = bid >> 1;
    const int bh = rest >> 5, chunk = rest & 31;
    const int tid = threadIdx.x;
    const unsigned short* __restrict__ src = arr ? vT : k;
    unsigned short* __restrict__ dst = arr ? bvrT : bkr;
    const float* __restrict__ Rb = R + (size_t)bh * 1024;

    const int e = chunk * 512 + tid * 2;
    const size_t base = (size_t)bh * 524288 + e;

    unsigned raw[32];
#pragma unroll
    for (int vb = 0; vb < 32; ++vb)
        raw[vb] = *(const unsigned*)(src + base + (size_t)vb * 16384);
    f32x2 val[32];
#pragma unroll
    for (int vb = 0; vb < 32; ++vb)
        val[vb] = f32x2{bf2f((unsigned short)raw[vb]), bf2f((unsigned short)(raw[vb] >> 16))};

#pragma unroll 2
    for (int u = 0; u < 32; ++u) {
        f32x2 a0 = {0.f, 0.f}, a1 = {0.f, 0.f}, a2 = {0.f, 0.f}, a3 = {0.f, 0.f};
#pragma unroll
        for (int g = 0; g < 2; ++g) {
            float4 r0 = *(const float4*)(Rb + u * 32 + g * 16);
            float4 r1 = *(const float4*)(Rb + u * 32 + g * 16 + 4);
            float4 r2 = *(const float4*)(Rb + u * 32 + g * 16 + 8);
            float4 r3 = *(const float4*)(Rb + u * 32 + g * 16 + 12);
            const int b0 = g * 16;
            a0 += r0.x * val[b0 + 0];  a0 += r0.y * val[b0 + 1];
            a0 += r0.z * val[b0 + 2];  a0 += r0.w * val[b0 + 3];
            a1 += r1.x * val[b0 + 4];  a1 += r1.y * val[b0 + 5];
            a1 += r1.z * val[b0 + 6];  a1 += r1.w * val[b0 + 7];
            a2 += r2.x * val[b0 + 8];  a2 += r2.y * val[b0 + 9];
            a2 += r2.z * val[b0 + 10]; a2 += r2.w * val[b0 + 11];
            a3 += r3.x * val[b0 + 12]; a3 += r3.y * val[b0 + 13];
            a3 += r3.z * val[b0 + 14]; a3 += r3.w * val[b0 + 15];
        }
        f32x2 a = (a0 + a1) + (a2 + a3);
        unsigned o = (unsigned)f2bf(a.x) | ((unsigned)f2bf(a.y) << 16);
        *(unsigned*)(dst + (size_t)bh * 524288 + (size_t)u * 16384 + e) = o;
    }
}

// ---------------- attention: 1024 blocks x 512 thr, 80KB LDS -> 2 blocks/CU ---------------
// FLAT softmax (bounded logits); denominators via ones-MFMA; counted vmcnt pipeline.
__global__ __launch_bounds__(512)
void attn_kernel(const unsigned short* __restrict__ q, const unsigned short* __restrict__ k,
                 const unsigned short* __restrict__ vT, const unsigned short* __restrict__ bkr,
                 const unsigned short* __restrict__ bvrT, unsigned short* __restrict__ ao) {
    __shared__ unsigned short KB[2][8192];   // 16KB: 64 kv-rows x 128 d (16 x 16B slots/row)
    __shared__ unsigned short VB[2][8192];   // 16KB: 128 d x 64 tl (8 x 16B slots/row)
    __shared__ unsigned short Ps[8][1024];   // 2KB/wave: 16 q x 64 kv, XOR-swizzled
    const int orig = blockIdx.x;
    const int bid = (orig & 7) * 128 + (orig >> 3);  // XCD-chunk swizzle (1024 % 8 == 0)
    const int bh = bid >> 5, u = bid & 31;
    const int tid = threadIdx.x, w = tid >> 6, lane = tid & 63;
    const int lr = lane & 15, lg = lane >> 4;
    const size_t bb = (size_t)bh * 524288 + (size_t)u * 16384;

#define STAGE_K(SRC, BUF)                                                        \
    _Pragma("unroll")                                                            \
    for (int i = 0; i < 2; ++i) {                                                \
        const int row_ = i * 32 + (tid >> 4);                                    \
        gload_lds16((SRC) + row_ * 128 + (((tid & 15) ^ (row_ & 7)) * 8),        \
                    (char*)KB[BUF] + i * 8192 + tid * 16);                       \
    }
#define STAGE_V(SRC, BUF)                                                        \
    _Pragma("unroll")                                                            \
    for (int i = 0; i < 2; ++i) {                                                \
        const int row_ = i * 64 + (tid >> 3);                                    \
        gload_lds16((SRC) + row_ * 128 + (((tid & 7) ^ (row_ & 7)) * 8),         \
                    (char*)VB[BUF] + i * 8192 + tid * 16);                       \
    }

    const unsigned short* qg = q + bb + (size_t)(w * 16) * 128;
    short8 aq[4];
#pragma unroll
    for (int kk = 0; kk < 4; ++kk)
        aq[kk] = *(const short8*)(qg + lr * 128 + kk * 32 + lg * 8);

    STAGE_K(bkr + bb, 0) STAGE_V(bvrT + bb, 0)          // chunk 0
    STAGE_K(bkr + bb + 8192, 1) STAGE_V(bvrT + bb + 64, 1)  // chunk 1

    short8 ones8;
#pragma unroll
    for (int i = 0; i < 8; ++i) ones8[i] = (short)0x3F80;   // bf16 1.0

    f32x4 oacc[8] = {};
    f32x4 lacc = {};                                        // row-sum accumulator

    asm volatile("s_waitcnt vmcnt(4)" ::: "memory");
    __builtin_amdgcn_sched_barrier(0);
    __builtin_amdgcn_s_barrier();

    unsigned short* Pw = Ps[w];

#pragma unroll
    for (int c = 0; c < 4; ++c) {
        const int cb = c & 1;
        // ---- QK^T over 64 kv ----
        f32x4 s[4] = {};
        __builtin_amdgcn_s_setprio(1);
#pragma unroll
        for (int kk = 0; kk < 4; ++kk)
#pragma unroll
            for (int ni = 0; ni < 4; ++ni) {
                short8 kb8 = *(const short8*)(&KB[cb][(ni * 16 + lr) * 128 +
                                              (((kk * 4 + lg) ^ (lr & 7)) * 8)]);
                s[ni] = __builtin_amdgcn_mfma_f32_16x16x32_bf16(aq[kk], kb8, s[ni], 0, 0, 0);
            }
        __builtin_amdgcn_s_setprio(0);

        // ---- flat exp + P write (swizzled) ----
#pragma unroll
        for (int r = 0; r < 4; ++r) {
            int prow = lg * 4 + r;
#pragma unroll
            for (int ni = 0; ni < 4; ++ni)
                Pw[prow * 64 + ((ni * 16 + lr) ^ ((prow & 7) << 3))] = f2bf(__expf(s[ni][r]));
        }

        // ---- PV + ones-MFMA denominators ----
        __builtin_amdgcn_s_setprio(1);
#pragma unroll
        for (int ks2 = 0; ks2 < 2; ++ks2) {
            short8 ap = *(const short8*)(&Pw[lr * 64 + ((ks2 * 32 + lg * 8) ^ ((lr & 7) << 3))]);
            lacc = __builtin_amdgcn_mfma_f32_16x16x32_bf16(ap, ones8, lacc, 0, 0, 0);
#pragma unroll
            for (int ni = 0; ni < 8; ++ni) {
                short8 bv8 = *(const short8*)(&VB[cb][(ni * 16 + lr) * 64 +
                                              (((ks2 * 4 + lg) ^ (lr & 7)) * 8)]);
                oacc[ni] = __builtin_amdgcn_mfma_f32_16x16x32_bf16(ap, bv8, oacc[ni], 0, 0, 0);
            }
        }
        __builtin_amdgcn_s_setprio(0);

        __builtin_amdgcn_s_barrier();            // all waves done with KB/VB[cb]
        if (c == 0) { STAGE_K(k + bb, 0) STAGE_V(vT + bb, 0) }
        else if (c == 1) { STAGE_K(k + bb + 8192, 1) STAGE_V(vT + bb + 64, 1) }
        if (c < 2) {
            asm volatile("s_waitcnt vmcnt(4)" ::: "memory");   // c+1 resident; c+2 flying
            __builtin_amdgcn_sched_barrier(0);
            __builtin_amdgcn_s_barrier();
        } else if (c == 2) {
            asm volatile("s_waitcnt vmcnt(0)" ::: "memory");   // chunk 3 resident (last)
            __builtin_amdgcn_sched_barrier(0);
            __builtin_amdgcn_s_barrier();
        }
    }

    // epilogue: ao[tok][h*128+dh] bf16
    const int b = bh >> 3, h = bh & 7;
#pragma unroll
    for (int r = 0; r < 4; ++r) {
        int row = w * 16 + lg * 4 + r;
        size_t rowbase = ((size_t)b * 4096 + u * 128 + row) * 1024 + h * 128;
        float inv = 1.f / lacc[r];
#pragma unroll
        for (int ni = 0; ni < 8; ++ni)
            ao[rowbase + ni * 16 + lr] = f2bf(oacc[ni][r] * inv);
    }
#undef STAGE_K
#undef STAGE_V
}

// ---------------- host ----------------
extern "C" void kernel_launch(void* const* d_in, const int* in_sizes, int n_in,
                              void* d_out, int out_size, void* d_ws, size_t ws_size,
                              hipStream_t stream) {
    (void)in_sizes; (void)n_in; (void)out_size; (void)ws_size;
    const float* x   = (const float*)d_in[0];
    const float* Wq  = (const float*)d_in[1];
    const float* Wkv = (const float*)d_in[2];
    const float* Wo  = (const float*)d_in[3];
    const float* bo  = (const float*)d_in[4];
    float* out = (float*)d_out;

    char* ws = (char*)d_ws;
    const size_t SZ_BIG = 33554432;
    unsigned short* xb    = (unsigned short*)(ws);                 // reused as attn_out
    unsigned short* qb    = (unsigned short*)(ws + SZ_BIG);
    unsigned short* kb    = (unsigned short*)(ws + 2 * SZ_BIG);
    unsigned short* vtb   = (unsigned short*)(ws + 3 * SZ_BIG);
    unsigned short* bkr   = (unsigned short*)(ws + 4 * SZ_BIG);
    unsigned short* bvrT  = (unsigned short*)(ws + 5 * SZ_BIG);
    size_t off = 6 * SZ_BIG;
    unsigned short* wqkvt = (unsigned short*)(ws + off); off += 6291456;  // [3072][1024] bf16
    unsigned short* wot   = (unsigned short*)(ws + off); off += 2097152;  // [1024][1024] bf16
    float* sq   = (float*)(ws + off); off += 524288;
    float* sk   = (float*)(ws + off); off += 524288;
    float* Rbuf = (float*)(ws + off); off += 131072;

    cast_x_kernel<<<4096, 256, 0, stream>>>(x, xb, 16777216);
    transpose_cast_kernel<<<dim3(32, 32), 256, 0, stream>>>(Wq, wqkvt, 1024, 1024);
    transpose_cast_kernel<<<dim3(32, 64), 256, 0, stream>>>(Wkv, wqkvt + 1048576, 1024, 2048);
    transpose_cast_kernel<<<dim3(32, 32), 256, 0, stream>>>(Wo, wot, 1024, 1024);

    gemmQKV<<<256, 512, 0, stream>>>(xb, wqkvt, qb, kb, vtb, sq, sk);

    sortnet_kernel<<<32, 1024, 0, stream>>>(sq, sk, Rbuf);
    mix_kernel<<<2048, 256, 0, stream>>>(kb, vtb, Rbuf, bkr, bvrT);

    attn_kernel<<<1024, 512, 0, stream>>>(qb, kb, vtb, bkr, bvrT, xb);

    gemmOut<<<256, 512, 0, stream>>>(xb, wot, out, bo);
}

// Round 9
// 257.146 us; speedup vs baseline: 1.0936x; 1.0936x over previous
//
#include <hip/hip_runtime.h>
#include <hip/hip_bf16.h>
#include <stdint.h>

typedef short short8 __attribute__((ext_vector_type(8)));
typedef float f32x4 __attribute__((ext_vector_type(4)));
typedef float f32x2 __attribute__((ext_vector_type(2)));

__device__ __forceinline__ unsigned short f2bf(float f) {
    unsigned u = __float_as_uint(f);
    u += 0x7fff + ((u >> 16) & 1);           // RNE
    return (unsigned short)(u >> 16);
}
__device__ __forceinline__ float bf2f(unsigned short h) {
    return __uint_as_float(((unsigned)h) << 16);
}

__device__ __forceinline__ void gload_lds16(const void* g, void* l) {
    __builtin_amdgcn_global_load_lds(
        (const __attribute__((address_space(1))) void*)g,
        (__attribute__((address_space(3))) void*)l, 16, 0, 0);
}

// ---------------- cast x (fp32 -> bf16 bits) ----------------
__global__ void cast_x_kernel(const float* __restrict__ x, unsigned short* __restrict__ xb, int n) {
    int i = (blockIdx.x * blockDim.x + threadIdx.x) * 4;
    int stride = gridDim.x * blockDim.x * 4;
    for (; i < n; i += stride) {
        float4 f = *(const float4*)(x + i);
        ushort4 o;
        o.x = f2bf(f.x); o.y = f2bf(f.y); o.z = f2bf(f.z); o.w = f2bf(f.w);
        *(ushort4*)(xb + i) = o;
    }
}

// ---------------- transpose + cast weights: W[k][n] fp32 -> Wt[n][k] bf16 ----------------
__global__ void transpose_cast_kernel(const float* __restrict__ W, unsigned short* __restrict__ Wt,
                                      int K, int N) {
    __shared__ unsigned short tile[32][33];
    int k0 = blockIdx.x * 32, n0 = blockIdx.y * 32;
    int tx = threadIdx.x & 31, ty = threadIdx.x >> 5;   // 32 x 8
#pragma unroll
    for (int i = 0; i < 32; i += 8)
        tile[ty + i][tx] = f2bf(W[(size_t)(k0 + ty + i) * N + n0 + tx]);
    __syncthreads();
#pragma unroll
    for (int i = 0; i < 32; i += 8)
        Wt[(size_t)(n0 + ty + i) * K + k0 + tx] = tile[tx][ty + i];
}

// ---------------- fused QKV GEMM: 768 blocks (64 m-tiles x 12 n-panels) -----------------
// One launch for q/k/vT: A=xb [16384][1024], B=wqkvt [3072][1024].  mode = panel>>2
// (0:q+mean, 1:k+mean, 2:vT), uniform per block.  Round-7 lesson: per-segment
// epilogues inside a persistent loop serialize against the counted vmcnt waits
// (stores count toward vmcnt on CDNA) and break write-combining (WRITE_SIZE 2x).
// Independent blocks with the epilogue at block end avoid both effects — this is
// the verified best configuration (~897 TF effective, the plain-HIP ceiling for
// this structure class at 16 K-steps / 1 block/CU).
__global__ __launch_bounds__(512, 4)
void gemmQKV(const unsigned short* __restrict__ A, const unsigned short* __restrict__ B,
             unsigned short* __restrict__ qb, unsigned short* __restrict__ kb,
             unsigned short* __restrict__ vtb, float* __restrict__ sq, float* __restrict__ sk) {
    __shared__ unsigned short Ssh[65536];   // A bufs: [0,32768) u16; B bufs: [32768,65536)
    const int tid = threadIdx.x;
    const int w = tid >> 6, lane = tid & 63;
    const int lr = lane & 15, lg = lane >> 4, r7 = lane & 7;
    const int wr = w >> 2, wc = w & 3;                  // 2x4 wave grid, wave tile 128x64
    const int orig = blockIdx.x;                        // 768 blocks
    const int lgc = (orig & 7) * 96 + (orig >> 3);      // XCD-chunked (768 % 8 == 0)
    const int m0 = (lgc / 12) * 256;
    const int p = lgc % 12;                             // n-panel
    const int nG = p * 256;                             // row offset in wqkvt
    const int mode = p >> 2;                            // 0:q 1:k 2:vT
    const int n0 = (p & 3) * 256;                       // local col in [0,1024)
    const int srow8 = lane >> 3;
    const int sgrp = (lane & 7) ^ srow8;                // pre-swizzled 16B group
    const unsigned short* gA = A + (size_t)(m0 + w * 16 + srow8) * 1024 + sgrp * 8;
    const unsigned short* gB = B + (size_t)(nG + w * 16 + srow8) * 1024 + sgrp * 8;

    f32x4 acc[8][4] = {};

#define SH(BUF, HALF, KT) {                                                              \
        const unsigned short* gp_ = ((HALF) < 2 ? gA : gB) +                             \
                                    (size_t)(((HALF) & 1) * 128) * 1024 + (KT);          \
        unsigned short* lp_ = Ssh + ((HALF) < 2 ? 0 : 32768) + (BUF) * 16384 +           \
                              ((HALF) & 1) * 8192 + w * 1024;                            \
        gload_lds16(gp_, lp_);                                                           \
        gload_lds16(gp_ + 8192, lp_ + 512);                                              \
    }

    SH(0, 0, 0) SH(0, 1, 0) SH(0, 2, 0) SH(0, 3, 0)
    SH(1, 0, 64) SH(1, 1, 64) SH(1, 2, 64)
    asm volatile("s_waitcnt vmcnt(6)" ::: "memory");    // tile0 resident
    __builtin_amdgcn_sched_barrier(0);
    __builtin_amdgcn_s_barrier();

#pragma unroll 2
    for (int t = 0; t < 16; ++t) {
        const int cur = t & 1;
        const unsigned short* Ab = Ssh + cur * 16384;
        const unsigned short* Bb = Ssh + 32768 + cur * 16384;
        const int kt1 = (t + 1) * 64, kt2 = (t + 2) * 64;
        short8 af[8][2], bf[4][2];

        // ---- P1: read af0-3 + bf0-1 (12) ; stage Bh1(t+1) ----
#pragma unroll
        for (int mi = 0; mi < 4; ++mi)
#pragma unroll
            for (int kk = 0; kk < 2; ++kk)
                af[mi][kk] = *(const short8*)(Ab + (wr * 128 + mi * 16 + lr) * 64 +
                                              (((kk << 2) | lg) ^ r7) * 8);
#pragma unroll
        for (int ni = 0; ni < 2; ++ni)
#pragma unroll
            for (int kk = 0; kk < 2; ++kk)
                bf[ni][kk] = *(const short8*)(Bb + (wc * 64 + ni * 16 + lr) * 64 +
                                              (((kk << 2) | lg) ^ r7) * 8);
        if (t + 1 < 16) { SH(cur ^ 1, 3, kt1) }
        asm volatile("s_waitcnt lgkmcnt(8)" ::: "memory");
        __builtin_amdgcn_sched_barrier(0);
        __builtin_amdgcn_s_barrier();
        asm volatile("s_waitcnt lgkmcnt(0)" ::: "memory");
        __builtin_amdgcn_sched_barrier(0);
        __builtin_amdgcn_s_setprio(1);
#pragma unroll
        for (int mi = 0; mi < 4; ++mi)
#pragma unroll
            for (int ni = 0; ni < 2; ++ni)
#pragma unroll
                for (int kk = 0; kk < 2; ++kk)
                    acc[mi][ni] = __builtin_amdgcn_mfma_f32_16x16x32_bf16(af[mi][kk], bf[ni][kk],
                                                                          acc[mi][ni], 0, 0, 0);
        __builtin_amdgcn_s_setprio(0);
        __builtin_amdgcn_s_barrier();

        // ---- P2: read af4-7 (8) ; stage Ah0(t+2) ----
#pragma unroll
        for (int mi = 4; mi < 8; ++mi)
#pragma unroll
            for (int kk = 0; kk < 2; ++kk)
                af[mi][kk] = *(const short8*)(Ab + (wr * 128 + mi * 16 + lr) * 64 +
                                              (((kk << 2) | lg) ^ r7) * 8);
        if (t + 2 < 16) { SH(cur, 0, kt2) }
        __builtin_amdgcn_s_barrier();
        asm volatile("s_waitcnt lgkmcnt(0)" ::: "memory");
        __builtin_amdgcn_sched_barrier(0);
        __builtin_amdgcn_s_setprio(1);
#pragma unroll
        for (int mi = 4; mi < 8; ++mi)
#pragma unroll
            for (int ni = 0; ni < 2; ++ni)
#pragma unroll
                for (int kk = 0; kk < 2; ++kk)
                    acc[mi][ni] = __builtin_amdgcn_mfma_f32_16x16x32_bf16(af[mi][kk], bf[ni][kk],
                                                                          acc[mi][ni], 0, 0, 0);
        __builtin_amdgcn_s_setprio(0);
        __builtin_amdgcn_s_barrier();

        // ---- P3: read bf2-3 (4) ; stage Ah1(t+2) ----
#pragma unroll
        for (int ni = 2; ni < 4; ++ni)
#pragma unroll
            for (int kk = 0; kk < 2; ++kk)
                bf[ni][kk] = *(const short8*)(Bb + (wc * 64 + ni * 16 + lr) * 64 +
                                              (((kk << 2) | lg) ^ r7) * 8);
        if (t + 2 < 16) { SH(cur, 1, kt2) }
        __builtin_amdgcn_s_barrier();
        asm volatile("s_waitcnt lgkmcnt(0)" ::: "memory");
        __builtin_amdgcn_sched_barrier(0);
        __builtin_amdgcn_s_setprio(1);
#pragma unroll
        for (int mi = 4; mi < 8; ++mi)
#pragma unroll
            for (int ni = 2; ni < 4; ++ni)
#pragma unroll
                for (int kk = 0; kk < 2; ++kk)
                    acc[mi][ni] = __builtin_amdgcn_mfma_f32_16x16x32_bf16(af[mi][kk], bf[ni][kk],
                                                                          acc[mi][ni], 0, 0, 0);
        __builtin_amdgcn_s_setprio(0);
        __builtin_amdgcn_s_barrier();

        // ---- P4: stage Bh0(t+2) ; MFMA from held regs ----
        if (t + 2 < 16) { SH(cur, 2, kt2) }
        __builtin_amdgcn_s_setprio(1);
#pragma unroll
        for (int mi = 0; mi < 4; ++mi)
#pragma unroll
            for (int ni = 2; ni < 4; ++ni)
#pragma unroll
                for (int kk = 0; kk < 2; ++kk)
                    acc[mi][ni] = __builtin_amdgcn_mfma_f32_16x16x32_bf16(af[mi][kk], bf[ni][kk],
                                                                          acc[mi][ni], 0, 0, 0);
        __builtin_amdgcn_s_setprio(0);
        if (t < 14) {
            asm volatile("s_waitcnt vmcnt(6)" ::: "memory");   // tile t+1 resident
            __builtin_amdgcn_sched_barrier(0);
            __builtin_amdgcn_s_barrier();
        } else if (t == 14) {
            asm volatile("s_waitcnt vmcnt(0)" ::: "memory");   // tile 15 fully resident
            __builtin_amdgcn_sched_barrier(0);
            __builtin_amdgcn_s_barrier();
        }
    }
#undef SH

    // ---- epilogue (runtime mode, uniform per block) ----
    if (mode == 2) {
#pragma unroll
        for (int mi = 0; mi < 8; ++mi)
#pragma unroll
            for (int ni = 0; ni < 4; ++ni) {
                // vT [bh][u][d][tloc]: pack (r, r+1) -> u32 (tl, tl+1 adjacent)
                int gm0 = m0 + wr * 128 + mi * 16 + lg * 4;
                int gn = n0 + wc * 64 + ni * 16 + lr;
                int b = gm0 >> 12, tt0 = gm0 & 4095, h = gn >> 7, dl = gn & 127;
                int u = tt0 >> 7, tl0 = tt0 & 127;
                size_t base = (size_t)(b * 8 + h) * 524288 + (size_t)u * 16384 + dl * 128 + tl0;
#pragma unroll
                for (int r = 0; r < 4; r += 2) {
                    unsigned pk = (unsigned)f2bf(acc[mi][ni][r]) |
                                  ((unsigned)f2bf(acc[mi][ni][r + 1]) << 16);
                    *(unsigned*)(vtb + base + r) = pk;
                }
            }
    } else {
        unsigned short* obf = (mode == 0) ? qb : kb;
        const float osc = (mode == 0) ? 0.08838834764831845f : 1.0f;
#pragma unroll
        for (int mi = 0; mi < 8; ++mi)
#pragma unroll
            for (int ni = 0; ni < 4; ++ni)
#pragma unroll
                for (int r = 0; r < 4; ++r) {
                    int gm = m0 + wr * 128 + mi * 16 + lg * 4 + r;
                    int gn = n0 + wc * 64 + ni * 16 + lr;
                    int b = gm >> 12, tt = gm & 4095, h = gn >> 7, dl = gn & 127;
                    obf[(size_t)(b * 8 + h) * 524288 + (size_t)tt * 128 + dl] =
                        f2bf(acc[mi][ni][r] * osc);
                }
        // fused bucket means: each (bh,u,d) owned by exactly one block & wave
        float* of = (mode == 0) ? sq : sk;
        const float sc = ((mode == 0) ? 0.08838834764831845f : 1.0f) / 128.f;
#pragma unroll
        for (int ni = 0; ni < 4; ++ni) {
            float ssum = 0.f;
#pragma unroll
            for (int mi = 0; mi < 8; ++mi)
#pragma unroll
                for (int r = 0; r < 4; ++r) ssum += acc[mi][ni][r];
            ssum += __shfl_xor(ssum, 16);
            ssum += __shfl_xor(ssum, 32);
            if (lane < 16) {
                int gn = n0 + wc * 64 + ni * 16 + lr;
                int h = gn >> 7, dl = gn & 127;
                int bh = (m0 >> 12) * 8 + h;
                int u = ((m0 & 4095) >> 7) + wr;
                of[(size_t)(bh * 32 + u) * 128 + dl] = ssum * sc;
            }
        }
    }
}

// ---------------- output GEMM (MODE 3 only): fp32 d_out [m][n] + bias[n] --------------
__global__ __launch_bounds__(512, 2)
void gemmOut(const unsigned short* __restrict__ A, const unsigned short* __restrict__ B,
             float* __restrict__ of, const float* __restrict__ bias) {
    __shared__ unsigned short Ssh[65536];
    const int tid = threadIdx.x;
    const int w = tid >> 6, lane = tid & 63;
    const int lr = lane & 15, lg = lane >> 4, r7 = lane & 7;
    const int wr = w >> 2, wc = w & 3;
    const int orig = blockIdx.x;                        // 256 blocks
    const int lgc = (orig & 7) * 32 + (orig >> 3);
    const int m0 = (lgc >> 2) * 256, n0 = (lgc & 3) * 256;
    const int srow8 = lane >> 3;
    const int sgrp = (lane & 7) ^ srow8;
    const unsigned short* gA = A + (size_t)(m0 + w * 16 + srow8) * 1024 + sgrp * 8;
    const unsigned short* gB = B + (size_t)(n0 + w * 16 + srow8) * 1024 + sgrp * 8;

    f32x4 acc[8][4] = {};

#define SH(BUF, HALF, KT) {                                                              \
        const unsigned short* gp_ = ((HALF) < 2 ? gA : gB) +                             \
                                    (size_t)(((HALF) & 1) * 128) * 1024 + (KT);          \
        unsigned short* lp_ = Ssh + ((HALF) < 2 ? 0 : 32768) + (BUF) * 16384 +           \
                              ((HALF) & 1) * 8192 + w * 1024;                            \
        gload_lds16(gp_, lp_);                                                           \
        gload_lds16(gp_ + 8192, lp_ + 512);                                              \
    }

    SH(0, 0, 0) SH(0, 1, 0) SH(0, 2, 0) SH(0, 3, 0)
    SH(1, 0, 64) SH(1, 1, 64) SH(1, 2, 64)
    asm volatile("s_waitcnt vmcnt(6)" ::: "memory");
    __builtin_amdgcn_sched_barrier(0);
    __builtin_amdgcn_s_barrier();

#pragma unroll 2
    for (int t = 0; t < 16; ++t) {
        const int cur = t & 1;
        const unsigned short* Ab = Ssh + cur * 16384;
        const unsigned short* Bb = Ssh + 32768 + cur * 16384;
        const int kt1 = (t + 1) * 64, kt2 = (t + 2) * 64;
        short8 af[8][2], bf[4][2];

#pragma unroll
        for (int mi = 0; mi < 4; ++mi)
#pragma unroll
            for (int kk = 0; kk < 2; ++kk)
                af[mi][kk] = *(const short8*)(Ab + (wr * 128 + mi * 16 + lr) * 64 +
                                              (((kk << 2) | lg) ^ r7) * 8);
#pragma unroll
        for (int ni = 0; ni < 2; ++ni)
#pragma unroll
            for (int kk = 0; kk < 2; ++kk)
                bf[ni][kk] = *(const short8*)(Bb + (wc * 64 + ni * 16 + lr) * 64 +
                                              (((kk << 2) | lg) ^ r7) * 8);
        if (t + 1 < 16) { SH(cur ^ 1, 3, kt1) }
        asm volatile("s_waitcnt lgkmcnt(8)" ::: "memory");
        __builtin_amdgcn_sched_barrier(0);
        __builtin_amdgcn_s_barrier();
        asm volatile("s_waitcnt lgkmcnt(0)" ::: "memory");
        __builtin_amdgcn_sched_barrier(0);
        __builtin_amdgcn_s_setprio(1);
#pragma unroll
        for (int mi = 0; mi < 4; ++mi)
#pragma unroll
            for (int ni = 0; ni < 2; ++ni)
#pragma unroll
                for (int kk = 0; kk < 2; ++kk)
                    acc[mi][ni] = __builtin_amdgcn_mfma_f32_16x16x32_bf16(af[mi][kk], bf[ni][kk],
                                                                          acc[mi][ni], 0, 0, 0);
        __builtin_amdgcn_s_setprio(0);
        __builtin_amdgcn_s_barrier();

#pragma unroll
        for (int mi = 4; mi < 8; ++mi)
#pragma unroll
            for (int kk = 0; kk < 2; ++kk)
                af[mi][kk] = *(const short8*)(Ab + (wr * 128 + mi * 16 + lr) * 64 +
                                              (((kk << 2) | lg) ^ r7) * 8);
        if (t + 2 < 16) { SH(cur, 0, kt2) }
        __builtin_amdgcn_s_barrier();
        asm volatile("s_waitcnt lgkmcnt(0)" ::: "memory");
        __builtin_amdgcn_sched_barrier(0);
        __builtin_amdgcn_s_setprio(1);
#pragma unroll
        for (int mi = 4; mi < 8; ++mi)
#pragma unroll
            for (int ni = 0; ni < 2; ++ni)
#pragma unroll
                for (int kk = 0; kk < 2; ++kk)
                    acc[mi][ni] = __builtin_amdgcn_mfma_f32_16x16x32_bf16(af[mi][kk], bf[ni][kk],
                                                                          acc[mi][ni], 0, 0, 0);
        __builtin_amdgcn_s_setprio(0);
        __builtin_amdgcn_s_barrier();

#pragma unroll
        for (int ni = 2; ni < 4; ++ni)
#pragma unroll
            for (int kk = 0; kk < 2; ++kk)
                bf[ni][kk] = *(const short8*)(Bb + (wc * 64 + ni * 16 + lr) * 64 +
                                              (((kk << 2) | lg) ^ r7) * 8);
        if (t + 2 < 16) { SH(cur, 1, kt2) }
        __builtin_amdgcn_s_barrier();
        asm volatile("s_waitcnt lgkmcnt(0)" ::: "memory");
        __builtin_amdgcn_sched_barrier(0);
        __builtin_amdgcn_s_setprio(1);
#pragma unroll
        for (int mi = 4; mi < 8; ++mi)
#pragma unroll
            for (int ni = 2; ni < 4; ++ni)
#pragma unroll
                for (int kk = 0; kk < 2; ++kk)
                    acc[mi][ni] = __builtin_amdgcn_mfma_f32_16x16x32_bf16(af[mi][kk], bf[ni][kk],
                                                                          acc[mi][ni], 0, 0, 0);
        __builtin_amdgcn_s_setprio(0);
        __builtin_amdgcn_s_barrier();

        if (t + 2 < 16) { SH(cur, 2, kt2) }
        __builtin_amdgcn_s_setprio(1);
#pragma unroll
        for (int mi = 0; mi < 4; ++mi)
#pragma unroll
            for (int ni = 2; ni < 4; ++ni)
#pragma unroll
                for (int kk = 0; kk < 2; ++kk)
                    acc[mi][ni] = __builtin_amdgcn_mfma_f32_16x16x32_bf16(af[mi][kk], bf[ni][kk],
                                                                          acc[mi][ni], 0, 0, 0);
        __builtin_amdgcn_s_setprio(0);
        if (t < 14) {
            asm volatile("s_waitcnt vmcnt(6)" ::: "memory");
            __builtin_amdgcn_sched_barrier(0);
            __builtin_amdgcn_s_barrier();
        } else if (t == 14) {
            asm volatile("s_waitcnt vmcnt(0)" ::: "memory");
            __builtin_amdgcn_sched_barrier(0);
            __builtin_amdgcn_s_barrier();
        }
    }
#undef SH

#pragma unroll
    for (int mi = 0; mi < 8; ++mi)
#pragma unroll
        for (int ni = 0; ni < 4; ++ni)
#pragma unroll
            for (int r = 0; r < 4; ++r) {
                int gm = m0 + wr * 128 + mi * 16 + lg * 4 + r;
                int gn = n0 + wc * 64 + ni * 16 + lr;
                of[(size_t)gm * 1024 + gn] = acc[mi][ni][r] + bias[gn];
            }
}

// ---------------- sortnet: R = softmax(sq.sk^T) (scale baked into q/sq) ----------------
__global__ void sortnet_kernel(const float* __restrict__ sq, const float* __restrict__ sk,
                               float* __restrict__ R) {
    __shared__ float qs[32 * 129];
    __shared__ float ks[32 * 129];
    int bh = blockIdx.x, tid = threadIdx.x;
    for (int i = tid; i < 4096; i += 1024) {
        int row = i >> 7, col = i & 127;
        qs[row * 129 + col] = sq[(size_t)bh * 4096 + i];
        ks[row * 129 + col] = sk[(size_t)bh * 4096 + i];
    }
    __syncthreads();
    int u = tid >> 5, v = tid & 31;
    float dot = 0.f;
    for (int d = 0; d < 128; ++d) dot += qs[u * 129 + d] * ks[v * 129 + d];
    float mx = dot;
    for (int m = 16; m >= 1; m >>= 1) mx = fmaxf(mx, __shfl_xor(mx, m, 32));
    float e = __expf(dot - mx);
    float s = e;
    for (int m = 16; m >= 1; m >>= 1) s += __shfl_xor(s, m, 32);
    R[(size_t)bh * 1024 + u * 32 + v] = e / s;
}

// ---------------- mix: bkr[u] = sum_v R[u][v] k[v]; bvrT likewise ----------------
__global__ __launch_bounds__(256, 4)
void mix_kernel(const unsigned short* __restrict__ k, const unsigned short* __restrict__ vT,
                const float* __restrict__ R, unsigned short* __restrict__ bkr,
                unsigned short* __restrict__ bvrT) {
    const int bid = blockIdx.x;                  // 2048 blocks
    const int arr = bid & 1;                     // 0: K, 1: V (interleaved)
    const int rest = bid >> 1;
    const int bh = rest >> 5, chunk = rest & 31;
    const int tid = threadIdx.x;
    const unsigned short* __restrict__ src = arr ? vT : k;
    unsigned short* __restrict__ dst = arr ? bvrT : bkr;
    const float* __restrict__ Rb = R + (size_t)bh * 1024;

    const int e = chunk * 512 + tid * 2;
    const size_t base = (size_t)bh * 524288 + e;

    unsigned raw[32];
#pragma unroll
    for (int vb = 0; vb < 32; ++vb)
        raw[vb] = *(const unsigned*)(src + base + (size_t)vb * 16384);
    f32x2 val[32];
#pragma unroll
    for (int vb = 0; vb < 32; ++vb)
        val[vb] = f32x2{bf2f((unsigned short)raw[vb]), bf2f((unsigned short)(raw[vb] >> 16))};

#pragma unroll 2
    for (int u = 0; u < 32; ++u) {
        f32x2 a0 = {0.f, 0.f}, a1 = {0.f, 0.f}, a2 = {0.f, 0.f}, a3 = {0.f, 0.f};
#pragma unroll
        for (int g = 0; g < 2; ++g) {
            float4 r0 = *(const float4*)(Rb + u * 32 + g * 16);
            float4 r1 = *(const float4*)(Rb + u * 32 + g * 16 + 4);
            float4 r2 = *(const float4*)(Rb + u * 32 + g * 16 + 8);
            float4 r3 = *(const float4*)(Rb + u * 32 + g * 16 + 12);
            const int b0 = g * 16;
            a0 += r0.x * val[b0 + 0];  a0 += r0.y * val[b0 + 1];
            a0 += r0.z * val[b0 + 2];  a0 += r0.w * val[b0 + 3];
            a1 += r1.x * val[b0 + 4];  a1 += r1.y * val[b0 + 5];
            a1 += r1.z * val[b0 + 6];  a1 += r1.w * val[b0 + 7];
            a2 += r2.x * val[b0 + 8];  a2 += r2.y * val[b0 + 9];
            a2 += r2.z * val[b0 + 10]; a2 += r2.w * val[b0 + 11];
            a3 += r3.x * val[b0 + 12]; a3 += r3.y * val[b0 + 13];
            a3 += r3.z * val[b0 + 14]; a3 += r3.w * val[b0 + 15];
        }
        f32x2 a = (a0 + a1) + (a2 + a3);
        unsigned o = (unsigned)f2bf(a.x) | ((unsigned)f2bf(a.y) << 16);
        *(unsigned*)(dst + (size_t)bh * 524288 + (size_t)u * 16384 + e) = o;
    }
}

// ---------------- attention: 1024 blocks x 512 thr, 80KB LDS -> 2 blocks/CU ---------------
// FLAT softmax (bounded logits); denominators via ones-MFMA; counted vmcnt pipeline.
__global__ __launch_bounds__(512)
void attn_kernel(const unsigned short* __restrict__ q, const unsigned short* __restrict__ k,
                 const unsigned short* __restrict__ vT, const unsigned short* __restrict__ bkr,
                 const unsigned short* __restrict__ bvrT, unsigned short* __restrict__ ao) {
    __shared__ unsigned short KB[2][8192];   // 16KB: 64 kv-rows x 128 d (16 x 16B slots/row)
    __shared__ unsigned short VB[2][8192];   // 16KB: 128 d x 64 tl (8 x 16B slots/row)
    __shared__ unsigned short Ps[8][1024];   // 2KB/wave: 16 q x 64 kv, XOR-swizzled
    const int orig = blockIdx.x;
    const int bid = (orig & 7) * 128 + (orig >> 3);  // XCD-chunk swizzle (1024 % 8 == 0)
    const int bh = bid >> 5, u = bid & 31;
    const int tid = threadIdx.x, w = tid >> 6, lane = tid & 63;
    const int lr = lane & 15, lg = lane >> 4;
    const size_t bb = (size_t)bh * 524288 + (size_t)u * 16384;

#define STAGE_K(SRC, BUF)                                                        \
    _Pragma("unroll")                                                            \
    for (int i = 0; i < 2; ++i) {                                                \
        const int row_ = i * 32 + (tid >> 4);                                    \
        gload_lds16((SRC) + row_ * 128 + (((tid & 15) ^ (row_ & 7)) * 8),        \
                    (char*)KB[BUF] + i * 8192 + tid * 16);                       \
    }
#define STAGE_V(SRC, BUF)                                                        \
    _Pragma("unroll")                                                            \
    for (int i = 0; i < 2; ++i) {                                                \
        const int row_ = i * 64 + (tid >> 3);                                    \
        gload_lds16((SRC) + row_ * 128 + (((tid & 7) ^ (row_ & 7)) * 8),         \
                    (char*)VB[BUF] + i * 8192 + tid * 16);                       \
    }

    const unsigned short* qg = q + bb + (size_t)(w * 16) * 128;
    short8 aq[4];
#pragma unroll
    for (int kk = 0; kk < 4; ++kk)
        aq[kk] = *(const short8*)(qg + lr * 128 + kk * 32 + lg * 8);

    STAGE_K(bkr + bb, 0) STAGE_V(bvrT + bb, 0)          // chunk 0
    STAGE_K(bkr + bb + 8192, 1) STAGE_V(bvrT + bb + 64, 1)  // chunk 1

    short8 ones8;
#pragma unroll
    for (int i = 0; i < 8; ++i) ones8[i] = (short)0x3F80;   // bf16 1.0

    f32x4 oacc[8] = {};
    f32x4 lacc = {};                                        // row-sum accumulator

    asm volatile("s_waitcnt vmcnt(4)" ::: "memory");
    __builtin_amdgcn_sched_barrier(0);
    __builtin_amdgcn_s_barrier();

    unsigned short* Pw = Ps[w];

#pragma unroll
    for (int c = 0; c < 4; ++c) {
        const int cb = c & 1;
        // ---- QK^T over 64 kv ----
        f32x4 s[4] = {};
        __builtin_amdgcn_s_setprio(1);
#pragma unroll
        for (int kk = 0; kk < 4; ++kk)
#pragma unroll
            for (int ni = 0; ni < 4; ++ni) {
                short8 kb8 = *(const short8*)(&KB[cb][(ni * 16 + lr) * 128 +
                                              (((kk * 4 + lg) ^ (lr & 7)) * 8)]);
                s[ni] = __builtin_amdgcn_mfma_f32_16x16x32_bf16(aq[kk], kb8, s[ni], 0, 0, 0);
            }
        __builtin_amdgcn_s_setprio(0);

        // ---- flat exp + P write (swizzled) ----
#pragma unroll
        for (int r = 0; r < 4; ++r) {
            int prow = lg * 4 + r;
#pragma unroll
            for (int ni = 0; ni < 4; ++ni)
                Pw[prow * 64 + ((ni * 16 + lr) ^ ((prow & 7) << 3))] = f2bf(__expf(s[ni][r]));
        }

        // ---- PV + ones-MFMA denominators ----
        __builtin_amdgcn_s_setprio(1);
#pragma unroll
        for (int ks2 = 0; ks2 < 2; ++ks2) {
            short8 ap = *(const short8*)(&Pw[lr * 64 + ((ks2 * 32 + lg * 8) ^ ((lr & 7) << 3))]);
            lacc = __builtin_amdgcn_mfma_f32_16x16x32_bf16(ap, ones8, lacc, 0, 0, 0);
#pragma unroll
            for (int ni = 0; ni < 8; ++ni) {
                short8 bv8 = *(const short8*)(&VB[cb][(ni * 16 + lr) * 64 +
                                              (((ks2 * 4 + lg) ^ (lr & 7)) * 8)]);
                oacc[ni] = __builtin_amdgcn_mfma_f32_16x16x32_bf16(ap, bv8, oacc[ni], 0, 0, 0);
            }
        }
        __builtin_amdgcn_s_setprio(0);

        __builtin_amdgcn_s_barrier();            // all waves done with KB/VB[cb]
        if (c == 0) { STAGE_K(k + bb, 0) STAGE_V(vT + bb, 0) }
        else if (c == 1) { STAGE_K(k + bb + 8192, 1) STAGE_V(vT + bb + 64, 1) }
        if (c < 2) {
            asm volatile("s_waitcnt vmcnt(4)" ::: "memory");   // c+1 resident; c+2 flying
            __builtin_amdgcn_sched_barrier(0);
            __builtin_amdgcn_s_barrier();
        } else if (c == 2) {
            asm volatile("s_waitcnt vmcnt(0)" ::: "memory");   // chunk 3 resident (last)
            __builtin_amdgcn_sched_barrier(0);
            __builtin_amdgcn_s_barrier();
        }
    }

    // epilogue: ao[tok][h*128+dh] bf16
    const int b = bh >> 3, h = bh & 7;
#pragma unroll
    for (int r = 0; r < 4; ++r) {
        int row = w * 16 + lg * 4 + r;
        size_t rowbase = ((size_t)b * 4096 + u * 128 + row) * 1024 + h * 128;
        float inv = 1.f / lacc[r];
#pragma unroll
        for (int ni = 0; ni < 8; ++ni)
            ao[rowbase + ni * 16 + lr] = f2bf(oacc[ni][r] * inv);
    }
#undef STAGE_K
#undef STAGE_V
}

// ---------------- host ----------------
extern "C" void kernel_launch(void* const* d_in, const int* in_sizes, int n_in,
                              void* d_out, int out_size, void* d_ws, size_t ws_size,
                              hipStream_t stream) {
    (void)in_sizes; (void)n_in; (void)out_size; (void)ws_size;
    const float* x   = (const float*)d_in[0];
    const float* Wq  = (const float*)d_in[1];
    const float* Wkv = (const float*)d_in[2];
    const float* Wo  = (const float*)d_in[3];
    const float* bo  = (const float*)d_in[4];
    float* out = (float*)d_out;

    char* ws = (char*)d_ws;
    const size_t SZ_BIG = 33554432;
    unsigned short* xb    = (unsigned short*)(ws);                 // reused as attn_out
    unsigned short* qb    = (unsigned short*)(ws + SZ_BIG);
    unsigned short* kb    = (unsigned short*)(ws + 2 * SZ_BIG);
    unsigned short* vtb   = (unsigned short*)(ws + 3 * SZ_BIG);
    unsigned short* bkr   = (unsigned short*)(ws + 4 * SZ_BIG);
    unsigned short* bvrT  = (unsigned short*)(ws + 5 * SZ_BIG);
    size_t off = 6 * SZ_BIG;
    unsigned short* wqkvt = (unsigned short*)(ws + off); off += 6291456;  // [3072][1024] bf16
    unsigned short* wot   = (unsigned short*)(ws + off); off += 2097152;  // [1024][1024] bf16
    float* sq   = (float*)(ws + off); off += 524288;
    float* sk   = (float*)(ws + off); off += 524288;
    float* Rbuf = (float*)(ws + off); off += 131072;

    cast_x_kernel<<<4096, 256, 0, stream>>>(x, xb, 16777216);
    transpose_cast_kernel<<<dim3(32, 32), 256, 0, stream>>>(Wq, wqkvt, 1024, 1024);
    transpose_cast_kernel<<<dim3(32, 64), 256, 0, stream>>>(Wkv, wqkvt + 1048576, 1024, 2048);
    transpose_cast_kernel<<<dim3(32, 32), 256, 0, stream>>>(Wo, wot, 1024, 1024);

    gemmQKV<<<768, 512, 0, stream>>>(xb, wqkvt, qb, kb, vtb, sq, sk);

    sortnet_kernel<<<32, 1024, 0, stream>>>(sq, sk, Rbuf);
    mix_kernel<<<2048, 256, 0, stream>>>(kb, vtb, Rbuf, bkr, bvrT);

    attn_kernel<<<1024, 512, 0, stream>>>(qb, kb, vtb, bkr, bvrT, xb);

    gemmOut<<<256, 512, 0, stream>>>(xb, wot, out, bo);
}